// Round 17
// baseline (150.342 us; speedup 1.0000x reference)
//
#include <hip/hip_runtime.h>

#define NN 100000
#define NE 600000
#define DD 128
#define BN_EPS 1e-5f
#define NB1 391                 // (NN+255)/256 scan blocks
#define NCV 12500               // convert blocks (8 rows each)
#define NFB 2344                // fill blocks
#define NBLK 782                // gather blocks: 512 thr, 8 waves, 1 tile/wave
#define NTILES 6250             // NN/16

typedef __attribute__((ext_vector_type(8))) short bf16x8;
typedef __attribute__((ext_vector_type(4))) float f32x4;

static __device__ __forceinline__ unsigned short f2bf(float f) {
    unsigned u = __float_as_uint(f);
    unsigned r = (u + 0x7FFFu + ((u >> 16) & 1u)) >> 16;   // RNE
    return (unsigned short)r;
}
static __device__ __forceinline__ float bflo(unsigned v) { return __uint_as_float(v << 16); }
static __device__ __forceinline__ float bfhi(unsigned v) { return __uint_as_float(v & 0xFFFF0000u); }

// ---------------------------------------------------------------- init: cnt=0, stats=0, W->Wt
__global__ __launch_bounds__(256) void k_init(int* __restrict__ cnt,
                                              float* __restrict__ stats,
                                              const float* __restrict__ W,
                                              unsigned short* __restrict__ Wt) {
    int i = blockIdx.x * 256 + threadIdx.x;
    if (i < NN) cnt[i] = 0;
    if (i < 256) stats[i] = 0.0f;
    if (i < DD * DD) {
        int k = i >> 7, c = i & 127;
        Wt[c * DD + k] = f2bf(W[i]);   // Wt[col][k]
    }
}

// ---------------------------------------------------------------- count incoming edges; rank = position in bucket
__global__ __launch_bounds__(256) void k_count(const int* __restrict__ dst,
                                               int* __restrict__ cnt,
                                               int* __restrict__ rank) {
    int e = blockIdx.x * 256 + threadIdx.x;
    if (e < NE) rank[e] = atomicAdd(&cnt[dst[e]], 1);
}

// ---------------------------------------------------------------- scan pass 1 over (cnt[i]+1)
__global__ __launch_bounds__(256) void k_scan1(const int* __restrict__ cnt,
                                               int* __restrict__ offs,
                                               int* __restrict__ bsum) {
    __shared__ int tmp[256];
    int tid = threadIdx.x;
    int i = blockIdx.x * 256 + tid;
    int v = (i < NN) ? (cnt[i] + 1) : 0;
    tmp[tid] = v;
    __syncthreads();
    #pragma unroll
    for (int d = 1; d < 256; d <<= 1) {
        int t = (tid >= d) ? tmp[tid - d] : 0;
        __syncthreads();
        tmp[tid] += t;
        __syncthreads();
    }
    if (i < NN) offs[i] = tmp[tid] - v;
    if (tid == 255) bsum[blockIdx.x] = tmp[255];
}

// ---------------------------------------------------------------- scan pass 2 (1 block)
__global__ __launch_bounds__(512) void k_scan2(int* __restrict__ bsum) {
    __shared__ int tmp[512];
    int tid = threadIdx.x;
    int v = (tid < NB1) ? bsum[tid] : 0;
    tmp[tid] = v;
    __syncthreads();
    #pragma unroll
    for (int d = 1; d < 512; d <<= 1) {
        int t = (tid >= d) ? tmp[tid - d] : 0;
        __syncthreads();
        tmp[tid] += t;
        __syncthreads();
    }
    if (tid < NB1) bsum[tid] = tmp[tid] - v;
}

// ---------------------------------------------------------------- scan pass 3: finalize offs, self edge, dinv
__global__ __launch_bounds__(256) void k_scan3(int* __restrict__ offs,
                                               const int* __restrict__ bsum,
                                               const int* __restrict__ cnt,
                                               float* __restrict__ dinv,
                                               int* __restrict__ srcs) {
    int i = blockIdx.x * 256 + threadIdx.x;
    if (i < NN) {
        int o = offs[i] + bsum[blockIdx.x];
        offs[i] = o;
        dinv[i] = rsqrtf((float)(cnt[i] + 1));
        srcs[o] = i;                     // self edge at slot 0
        if (i == 0) offs[NN] = NE + NN;  // sentinel
    }
}

// ---------------------------------------------------------------- merged: CSR fill (atomic-free) || xn = bf16(x*dinv)
__global__ __launch_bounds__(256) void k_cvfill(const float* __restrict__ x,
                                                const float* __restrict__ dinv,
                                                unsigned short* __restrict__ xn,
                                                const int* __restrict__ src,
                                                const int* __restrict__ dst,
                                                const int* __restrict__ rank,
                                                const int* __restrict__ offs,
                                                int* __restrict__ srcs) {
    int bid = blockIdx.x;
    if (bid < NFB) {
        int e = bid * 256 + threadIdx.x;
        if (e < NE) {
            int t = dst[e];
            srcs[offs[t] + 1 + rank[e]] = src[e];   // pure scatter, no RMW
        }
    } else {
        int r  = (bid - NFB) * 8 + (threadIdx.x >> 5);
        int c4 = threadIdx.x & 31;
        float di = dinv[r];
        float4 v = ((const float4*)x)[(size_t)r * 32 + c4];
        unsigned p0 = ((unsigned)f2bf(v.y * di) << 16) | f2bf(v.x * di);
        unsigned p1 = ((unsigned)f2bf(v.w * di) << 16) | f2bf(v.z * di);
        ((uint2*)xn)[(size_t)r * 32 + c4] = make_uint2(p0, p1);
    }
}

// ---------------------------------------------------------------- fused gather + MFMA-GEMM + bias + stats
// R16's prefetch idea, exec-mask-SAFE version: the edge loop is WAVE-UNIFORM
// (all lanes iterate to nmax = max degree over the tile's 16 nodes), so every
// __shfl executes with all 64 lanes active. Overshoot lanes (k >= n) use a
// CLAMPED index min(k, n-1) (valid, L1-resident) and weight 0 via fmaf —
// no divergent branch anywhere in the loop. R16's bug: FETCH_SRC shfls sat
// inside per-lane-bounded loops; early-exiting lanes went inactive and
// bpermute returned garbage from them (absmax 9.04).
// Store epilogue r-outer/nt-inner kept (kills ~51 MB out-RFO seen in R15).
__global__ __launch_bounds__(512) void k_gather(const int* __restrict__ offs,
                                                const int* __restrict__ srcs,
                                                const unsigned short* __restrict__ xn,
                                                const float* __restrict__ dinv,
                                                const float* __restrict__ b,
                                                const unsigned short* __restrict__ Wt,
                                                float* __restrict__ out,
                                                float* __restrict__ partial) {
    __shared__ uint4 Wl4[2048];                   // 32 KB swizzled W (reused for stats at the end)
    const int tid  = threadIdx.x;
    const int wid  = tid >> 6;        // 0..7
    const int lane = tid & 63;
    const int lm   = lane & 15;       // node-row within tile / A-row / B-col
    const int lk   = lane >> 4;       // k-chunk 0..3
    char* Wl = (char*)Wl4;

    // stage W: swizzle byte(row, c16) = row*256 + ((c16 ^ (row&7)) << 4)
    #pragma unroll
    for (int it = 0; it < 4; ++it) {
        int chunk = it * 512 + tid;            // 0..2047
        int row = chunk >> 4, c16 = chunk & 15;
        uint4 v = *(const uint4*)(Wt + row * DD + c16 * 8);
        *(uint4*)(Wl + row * 256 + ((c16 ^ (row & 7)) << 4)) = v;
    }
    float bb[8];
    #pragma unroll
    for (int nt = 0; nt < 8; ++nt) bb[nt] = b[nt * 16 + lm];
    __syncthreads();

    float s8[8], ss8[8];
    #pragma unroll
    for (int j = 0; j < 8; ++j) { s8[j] = 0.0f; ss8[j] = 0.0f; }
    const uint4* xn4 = (const uint4*)xn;

    const int tile = blockIdx.x * 8 + wid;     // one tile per wave
    if (tile < NTILES) {                       // wave-uniform guard
        const int nbase = tile * 16;

        int   ol = offs[nbase + (lane <= 16 ? lane : 16)];
        float dv = (lane < 16) ? dinv[nbase + lane] : 0.0f;
        int   beg = __shfl(ol, lm);
        int   n   = __shfl(ol, lm + 1) - beg;  // n >= 1 (self edge)
        float di  = __shfl(dv, lm);

        // wave-uniform max degree over the tile's 16 nodes (n is constant
        // across lk groups, so reducing within each 16-lane group suffices)
        int nmax = n;
        #pragma unroll
        for (int m = 1; m < 16; m <<= 1) nmax = max(nmax, __shfl_xor(nmax, m));

        // ---- prefetch the tile's edge slots (contiguous in srcs) into registers
        const int tb = __shfl(ol, 0);          // tile slot range [tb, te)
        const int te = __shfl(ol, 16);
        const int nE = te - tb;                // ~112 avg
        int p0 = (lane < nE)       ? srcs[tb + lane]       : 0;
        int p1 = (64 + lane < nE)  ? srcs[tb + 64 + lane]  : 0;
        int p2 = (128 + lane < nE) ? srcs[tb + 128 + lane] : 0;
        const int lbase = beg - tb;            // this node's first slot, tile-local

        float acc[4][8];
        #pragma unroll
        for (int ks = 0; ks < 4; ++ks)
            #pragma unroll
            for (int j = 0; j < 8; ++j) acc[ks][j] = 0.0f;

        // per-edge src fetch; caller guarantees all 64 lanes active
        #define FETCH_SRC(li, g)                                              \
            ({ int _li = (li);                                                \
               int _c0 = __shfl(p0, _li & 63);                                \
               int _c1 = __shfl(p1, _li & 63);                                \
               int _c2 = __shfl(p2, _li & 63);                                \
               (_li < 64) ? _c0 : (_li < 128) ? _c1 : (_li < 192) ? _c2       \
                          : srcs[(g)]; })

        int k = 0;
        for (; k + 3 <= nmax; k += 3) {        // uniform bound; 12 x 16B loads in flight
            int i0 = min(k,     n - 1), i1 = min(k + 1, n - 1), i2 = min(k + 2, n - 1);
            float w0 = (k     < n) ? 1.0f : 0.0f;
            float w1 = (k + 1 < n) ? 1.0f : 0.0f;
            float w2 = (k + 2 < n) ? 1.0f : 0.0f;
            int s0 = FETCH_SRC(lbase + i0, beg + i0);
            int s1 = FETCH_SRC(lbase + i1, beg + i1);
            int s2 = FETCH_SRC(lbase + i2, beg + i2);
            uint4 v0[4], v1[4], v2[4];
            #pragma unroll
            for (int ks = 0; ks < 4; ++ks) v0[ks] = xn4[(size_t)s0 * 16 + ks * 4 + lk];
            #pragma unroll
            for (int ks = 0; ks < 4; ++ks) v1[ks] = xn4[(size_t)s1 * 16 + ks * 4 + lk];
            #pragma unroll
            for (int ks = 0; ks < 4; ++ks) v2[ks] = xn4[(size_t)s2 * 16 + ks * 4 + lk];
            #pragma unroll
            for (int ks = 0; ks < 4; ++ks) {
                acc[ks][0] = fmaf(bflo(v2[ks].x), w2, fmaf(bflo(v1[ks].x), w1, fmaf(bflo(v0[ks].x), w0, acc[ks][0])));
                acc[ks][1] = fmaf(bfhi(v2[ks].x), w2, fmaf(bfhi(v1[ks].x), w1, fmaf(bfhi(v0[ks].x), w0, acc[ks][1])));
                acc[ks][2] = fmaf(bflo(v2[ks].y), w2, fmaf(bflo(v1[ks].y), w1, fmaf(bflo(v0[ks].y), w0, acc[ks][2])));
                acc[ks][3] = fmaf(bfhi(v2[ks].y), w2, fmaf(bfhi(v1[ks].y), w1, fmaf(bfhi(v0[ks].y), w0, acc[ks][3])));
                acc[ks][4] = fmaf(bflo(v2[ks].z), w2, fmaf(bflo(v1[ks].z), w1, fmaf(bflo(v0[ks].z), w0, acc[ks][4])));
                acc[ks][5] = fmaf(bfhi(v2[ks].z), w2, fmaf(bfhi(v1[ks].z), w1, fmaf(bfhi(v0[ks].z), w0, acc[ks][5])));
                acc[ks][6] = fmaf(bflo(v2[ks].w), w2, fmaf(bflo(v1[ks].w), w1, fmaf(bflo(v0[ks].w), w0, acc[ks][6])));
                acc[ks][7] = fmaf(bfhi(v2[ks].w), w2, fmaf(bfhi(v1[ks].w), w1, fmaf(bfhi(v0[ks].w), w0, acc[ks][7])));
            }
        }
        for (; k < nmax; ++k) {                // uniform tail (0-2 iters)
            int   i0 = min(k, n - 1);
            float w0 = (k < n) ? 1.0f : 0.0f;
            int   s0 = FETCH_SRC(lbase + i0, beg + i0);
            #pragma unroll
            for (int ks = 0; ks < 4; ++ks) {
                uint4 v = xn4[(size_t)s0 * 16 + ks * 4 + lk];
                acc[ks][0] = fmaf(bflo(v.x), w0, acc[ks][0]);
                acc[ks][1] = fmaf(bfhi(v.x), w0, acc[ks][1]);
                acc[ks][2] = fmaf(bflo(v.y), w0, acc[ks][2]);
                acc[ks][3] = fmaf(bfhi(v.y), w0, acc[ks][3]);
                acc[ks][4] = fmaf(bflo(v.z), w0, acc[ks][4]);
                acc[ks][5] = fmaf(bfhi(v.z), w0, acc[ks][5]);
                acc[ks][6] = fmaf(bflo(v.w), w0, acc[ks][6]);
                acc[ks][7] = fmaf(bfhi(v.w), w0, acc[ks][7]);
            }
        }
        #undef FETCH_SRC

        // scale by dinv[node], convert to A-fragments
        bf16x8 a[4];
        #pragma unroll
        for (int ks = 0; ks < 4; ++ks)
            #pragma unroll
            for (int j = 0; j < 8; ++j) a[ks][j] = (short)f2bf(acc[ks][j] * di);

        f32x4 dacc[8];
        #pragma unroll
        for (int nt = 0; nt < 8; ++nt) dacc[nt] = (f32x4){0.f, 0.f, 0.f, 0.f};
        #pragma unroll
        for (int ks = 0; ks < 4; ++ks)
            #pragma unroll
            for (int nt = 0; nt < 8; ++nt) {
                int brow = nt * 16 + lm;
                bf16x8 bfr = *(const bf16x8*)(Wl + brow * 256 + ((ks * 64 + lk * 16) ^ ((brow & 7) << 4)));
                dacc[nt] = __builtin_amdgcn_mfma_f32_16x16x32_bf16(a[ks], bfr, dacc[nt], 0, 0, 0);
            }

        // epilogue: D row = lk*4+r, col = nt*16+lm.
        // r OUTER, nt INNER: consecutive stores fill each 128B line -> no RFO.
        #pragma unroll
        for (int r = 0; r < 4; ++r) {
            const size_t rowoff = (size_t)(nbase + lk * 4 + r) * DD;
            #pragma unroll
            for (int nt = 0; nt < 8; ++nt) {
                float val = dacc[nt][r] + bb[nt];
                out[rowoff + nt * 16 + lm] = val;
                s8[nt] += val; ss8[nt] += val * val;
            }
        }
    }

    // ---- stats: reduce across lk groups, then across waves (reusing W LDS)
    #pragma unroll
    for (int nt = 0; nt < 8; ++nt) {
        s8[nt]  += __shfl_xor(s8[nt], 16);  s8[nt]  += __shfl_xor(s8[nt], 32);
        ss8[nt] += __shfl_xor(ss8[nt], 16); ss8[nt] += __shfl_xor(ss8[nt], 32);
    }
    __syncthreads();                     // all waves done reading W
    float* sp = (float*)Wl4;             // [8][128] sums | [8][128] sumsq = 8 KB
    if (lk == 0) {
        #pragma unroll
        for (int nt = 0; nt < 8; ++nt) {
            sp[wid * 128 + nt * 16 + lm]        = s8[nt];
            sp[1024 + wid * 128 + nt * 16 + lm] = ss8[nt];
        }
    }
    __syncthreads();
    if (tid < 128) {
        float a = 0.0f, c = 0.0f;
        #pragma unroll
        for (int w = 0; w < 8; ++w) { a += sp[w * 128 + tid]; c += sp[1024 + w * 128 + tid]; }
        partial[(size_t)blockIdx.x * 256 + tid]       = a;
        partial[(size_t)blockIdx.x * 256 + 128 + tid] = c;
    }
}

// ---------------------------------------------------------------- reduce partials -> stats[256]
__global__ __launch_bounds__(256) void k_red(const float* __restrict__ partial,
                                             float* __restrict__ stats) {
    int tid = threadIdx.x;
    float a = 0.0f;
    for (int r = blockIdx.x; r < NBLK; r += 64)
        a += partial[(size_t)r * 256 + tid];
    unsafeAtomicAdd(&stats[tid], a);
}

// ---------------------------------------------------------------- BN apply + ReLU + residual
__global__ __launch_bounds__(256) void k_final(float* __restrict__ out,
                                               const float* __restrict__ x,
                                               const float* __restrict__ gamma,
                                               const float* __restrict__ beta,
                                               const float* __restrict__ stats) {
    int idx = blockIdx.x * 256 + threadIdx.x;
    if (idx >= NN * DD / 4) return;
    int c4 = idx & 31;

    const float invN = 1.0f / (float)NN;
    float4 sm  = ((const float4*)stats)[c4];
    float4 sq  = ((const float4*)stats)[32 + c4];
    float4 g   = ((const float4*)gamma)[c4];
    float4 be  = ((const float4*)beta)[c4];
    float4 v   = ((float4*)out)[idx];
    float4 xr  = ((const float4*)x)[idx];

    float m0 = sm.x * invN, m1 = sm.y * invN, m2 = sm.z * invN, m3 = sm.w * invN;
    float r0 = rsqrtf(sq.x * invN - m0 * m0 + BN_EPS);
    float r1 = rsqrtf(sq.y * invN - m1 * m1 + BN_EPS);
    float r2 = rsqrtf(sq.z * invN - m2 * m2 + BN_EPS);
    float r3 = rsqrtf(sq.w * invN - m3 * m3 + BN_EPS);

    float4 o;
    o.x = fmaxf((v.x - m0) * r0 * g.x + be.x, 0.0f) + xr.x;
    o.y = fmaxf((v.y - m1) * r1 * g.y + be.y, 0.0f) + xr.y;
    o.z = fmaxf((v.z - m2) * r2 * g.z + be.z, 0.0f) + xr.z;
    o.w = fmaxf((v.w - m3) * r3 * g.w + be.w, 0.0f) + xr.w;
    ((float4*)out)[idx] = o;
}

// ---------------------------------------------------------------- launch
extern "C" void kernel_launch(void* const* d_in, const int* in_sizes, int n_in,
                              void* d_out, int out_size, void* d_ws, size_t ws_size,
                              hipStream_t stream) {
    const float* x     = (const float*)d_in[0];
    const int*   ei    = (const int*)d_in[1];    // [2, NE]
    const float* W     = (const float*)d_in[2];
    const float* b     = (const float*)d_in[3];
    const float* gamma = (const float*)d_in[4];
    const float* beta  = (const float*)d_in[5];
    float*       out   = (float*)d_out;

    char*  base = (char*)d_ws;
    size_t off  = 0;
    auto carve = [&](size_t bytes) -> void* {
        void* p = base + off;
        off = (off + bytes + 255) & ~(size_t)255;
        return p;
    };
    unsigned short* xn    = (unsigned short*)carve((size_t)NN * DD * 2);   // 25.6 MB
    float*          dinv  = (float*)carve((size_t)NN * 4);
    float*          stats = (float*)carve(256 * 4);
    int*            cnt   = (int*)carve((size_t)NN * 4);
    int*            offs  = (int*)carve((size_t)(NN + 1) * 4);
    int*            rank  = (int*)carve((size_t)NE * 4);                   // 2.4 MB
    int*            bsum  = (int*)carve(2048);
    int*            srcs  = (int*)carve((size_t)(NE + NN) * 4);            // 2.8 MB
    unsigned short* Wt    = (unsigned short*)carve(DD * DD * 2);
    float*          partial = (float*)carve((size_t)NBLK * 256 * 4);       // 0.8 MB

    const int* src = ei;        // edge_index[0]
    const int* dst = ei + NE;   // edge_index[1]

    k_init   <<<NB1, 256, 0, stream>>>(cnt, stats, W, Wt);
    k_count  <<<(NE + 255) / 256, 256, 0, stream>>>(dst, cnt, rank);
    k_scan1  <<<NB1, 256, 0, stream>>>(cnt, offs, bsum);
    k_scan2  <<<1, 512, 0, stream>>>(bsum);
    k_scan3  <<<NB1, 256, 0, stream>>>(offs, bsum, cnt, dinv, srcs);
    k_cvfill <<<NFB + NCV, 256, 0, stream>>>(x, dinv, xn, src, dst, rank, offs, srcs);
    k_gather <<<NBLK, 512, 0, stream>>>(offs, srcs, xn, dinv, b, Wt, out, partial);
    k_red    <<<64, 256, 0, stream>>>(partial, stats);
    k_final  <<<(NN * DD / 4 + 255) / 256, 256, 0, stream>>>(out, x, gamma, beta, stats);
}

// Round 18
// 138.129 us; speedup vs baseline: 1.0884x; 1.0884x over previous
//
#include <hip/hip_runtime.h>

#define NN 100000
#define NE 600000
#define DD 128
#define BN_EPS 1e-5f
#define NB1 391                 // (NN+255)/256 scan blocks
#define NCV 12500               // convert blocks (8 rows each)
#define NFB 2344                // fill blocks
#define NBLK 782                // gather blocks: 512 thr, 8 waves, 1 tile/wave
#define NTILES 6250             // NN/16
#define SCAP 192                // per-wave staged edge slots (LDS)

typedef __attribute__((ext_vector_type(8))) short bf16x8;
typedef __attribute__((ext_vector_type(4))) float f32x4;

static __device__ __forceinline__ unsigned short f2bf(float f) {
    unsigned u = __float_as_uint(f);
    unsigned r = (u + 0x7FFFu + ((u >> 16) & 1u)) >> 16;   // RNE
    return (unsigned short)r;
}
static __device__ __forceinline__ float bflo(unsigned v) { return __uint_as_float(v << 16); }
static __device__ __forceinline__ float bfhi(unsigned v) { return __uint_as_float(v & 0xFFFF0000u); }

// ---------------------------------------------------------------- init: cnt=0, stats=0, W->Wt
__global__ __launch_bounds__(256) void k_init(int* __restrict__ cnt,
                                              float* __restrict__ stats,
                                              const float* __restrict__ W,
                                              unsigned short* __restrict__ Wt) {
    int i = blockIdx.x * 256 + threadIdx.x;
    if (i < NN) cnt[i] = 0;
    if (i < 256) stats[i] = 0.0f;
    if (i < DD * DD) {
        int k = i >> 7, c = i & 127;
        Wt[c * DD + k] = f2bf(W[i]);   // Wt[col][k]
    }
}

// ---------------------------------------------------------------- count incoming edges; rank = position in bucket
__global__ __launch_bounds__(256) void k_count(const int* __restrict__ dst,
                                               int* __restrict__ cnt,
                                               int* __restrict__ rank) {
    int e = blockIdx.x * 256 + threadIdx.x;
    if (e < NE) rank[e] = atomicAdd(&cnt[dst[e]], 1);
}

// ---------------------------------------------------------------- scan pass 1 over (cnt[i]+1)
__global__ __launch_bounds__(256) void k_scan1(const int* __restrict__ cnt,
                                               int* __restrict__ offs,
                                               int* __restrict__ bsum) {
    __shared__ int tmp[256];
    int tid = threadIdx.x;
    int i = blockIdx.x * 256 + tid;
    int v = (i < NN) ? (cnt[i] + 1) : 0;
    tmp[tid] = v;
    __syncthreads();
    #pragma unroll
    for (int d = 1; d < 256; d <<= 1) {
        int t = (tid >= d) ? tmp[tid - d] : 0;
        __syncthreads();
        tmp[tid] += t;
        __syncthreads();
    }
    if (i < NN) offs[i] = tmp[tid] - v;
    if (tid == 255) bsum[blockIdx.x] = tmp[255];
}

// ---------------------------------------------------------------- scan pass 2 (1 block)
__global__ __launch_bounds__(512) void k_scan2(int* __restrict__ bsum) {
    __shared__ int tmp[512];
    int tid = threadIdx.x;
    int v = (tid < NB1) ? bsum[tid] : 0;
    tmp[tid] = v;
    __syncthreads();
    #pragma unroll
    for (int d = 1; d < 512; d <<= 1) {
        int t = (tid >= d) ? tmp[tid - d] : 0;
        __syncthreads();
        tmp[tid] += t;
        __syncthreads();
    }
    if (tid < NB1) bsum[tid] = tmp[tid] - v;
}

// ---------------------------------------------------------------- scan pass 3: finalize offs, self edge, dinv
__global__ __launch_bounds__(256) void k_scan3(int* __restrict__ offs,
                                               const int* __restrict__ bsum,
                                               const int* __restrict__ cnt,
                                               float* __restrict__ dinv,
                                               int* __restrict__ srcs) {
    int i = blockIdx.x * 256 + threadIdx.x;
    if (i < NN) {
        int o = offs[i] + bsum[blockIdx.x];
        offs[i] = o;
        dinv[i] = rsqrtf((float)(cnt[i] + 1));
        srcs[o] = i;                     // self edge at slot 0
        if (i == 0) offs[NN] = NE + NN;  // sentinel
    }
}

// ---------------------------------------------------------------- merged: CSR fill (atomic-free) || xn = bf16(x*dinv)
__global__ __launch_bounds__(256) void k_cvfill(const float* __restrict__ x,
                                                const float* __restrict__ dinv,
                                                unsigned short* __restrict__ xn,
                                                const int* __restrict__ src,
                                                const int* __restrict__ dst,
                                                const int* __restrict__ rank,
                                                const int* __restrict__ offs,
                                                int* __restrict__ srcs) {
    int bid = blockIdx.x;
    if (bid < NFB) {
        int e = bid * 256 + threadIdx.x;
        if (e < NE) {
            int t = dst[e];
            srcs[offs[t] + 1 + rank[e]] = src[e];   // pure scatter, no RMW
        }
    } else {
        int r  = (bid - NFB) * 8 + (threadIdx.x >> 5);
        int c4 = threadIdx.x & 31;
        float di = dinv[r];
        float4 v = ((const float4*)x)[(size_t)r * 32 + c4];
        unsigned p0 = ((unsigned)f2bf(v.y * di) << 16) | f2bf(v.x * di);
        unsigned p1 = ((unsigned)f2bf(v.w * di) << 16) | f2bf(v.z * di);
        ((uint2*)xn)[(size_t)r * 32 + c4] = make_uint2(p0, p1);
    }
}

// ---------------------------------------------------------------- fused gather + MFMA-GEMM + bias + stats
// EXACT R13 inner loop (per-lane divergent 2-edge unroll, no shfls in loop —
// 49.5 us proven) + srcs staged in per-wave LDS: the tile's contiguous slot
// range [tb,te) is copied by 3 coalesced wave-loads into slds[wid][192];
// the loop's chain-head scattered-global srcs load becomes a ~120cy LDS read
// (guarded global fallback for tiles >192 slots, P~1e-10). R16/R17 lessons:
// no shfl in divergent loops (exec-mask garbage); no clamp-overshoot
// (1.7x load amplification).
__global__ __launch_bounds__(512) void k_gather(const int* __restrict__ offs,
                                                const int* __restrict__ srcs,
                                                const unsigned short* __restrict__ xn,
                                                const float* __restrict__ dinv,
                                                const float* __restrict__ b,
                                                const unsigned short* __restrict__ Wt,
                                                float* __restrict__ out,
                                                float* __restrict__ partial) {
    __shared__ uint4 Wl4[2048];                   // 32 KB swizzled W (reused for stats at the end)
    __shared__ int   slds[8][SCAP];               // 6 KB staged edge slots (per wave)
    const int tid  = threadIdx.x;
    const int wid  = tid >> 6;        // 0..7
    const int lane = tid & 63;
    const int lm   = lane & 15;       // node-row within tile / A-row / B-col
    const int lk   = lane >> 4;       // k-chunk 0..3
    char* Wl = (char*)Wl4;

    // stage W: swizzle byte(row, c16) = row*256 + ((c16 ^ (row&7)) << 4)
    #pragma unroll
    for (int it = 0; it < 4; ++it) {
        int chunk = it * 512 + tid;            // 0..2047
        int row = chunk >> 4, c16 = chunk & 15;
        uint4 v = *(const uint4*)(Wt + row * DD + c16 * 8);
        *(uint4*)(Wl + row * 256 + ((c16 ^ (row & 7)) << 4)) = v;
    }
    float bb[8];
    #pragma unroll
    for (int nt = 0; nt < 8; ++nt) bb[nt] = b[nt * 16 + lm];
    __syncthreads();

    float s8[8], ss8[8];
    #pragma unroll
    for (int j = 0; j < 8; ++j) { s8[j] = 0.0f; ss8[j] = 0.0f; }
    const uint4* xn4 = (const uint4*)xn;

    const int tile = blockIdx.x * 8 + wid;     // one tile per wave
    if (tile < NTILES) {                       // wave-uniform guard
        const int nbase = tile * 16;

        int   ol = offs[nbase + (lane <= 16 ? lane : 16)];
        float dv = (lane < 16) ? dinv[nbase + lane] : 0.0f;
        int   beg = __shfl(ol, lm);
        int   n   = __shfl(ol, lm + 1) - beg;  // n >= 1 (self edge)
        float di  = __shfl(dv, lm);

        // stage this wave's edge slots (contiguous) into its own LDS buffer
        const int tb = __shfl(ol, 0);
        const int nE = __shfl(ol, 16) - tb;    // ~112 avg
        #pragma unroll
        for (int r2 = 0; r2 < 3; ++r2) {
            int idx2 = r2 * 64 + lane;
            if (idx2 < nE && idx2 < SCAP) slds[wid][idx2] = srcs[tb + idx2];
        }
        const int lbase = beg - tb;            // this node's first slot, tile-local

        float acc[4][8];
        #pragma unroll
        for (int ks = 0; ks < 4; ++ks)
            #pragma unroll
            for (int j = 0; j < 8; ++j) acc[ks][j] = 0.0f;

        int k = 0;
        for (; k + 2 <= n; k += 2) {           // 2 edges in flight (R13-proven)
            int li0 = lbase + k, li1 = lbase + k + 1;
            int s0 = (li0 < SCAP) ? slds[wid][li0] : srcs[beg + k];
            int s1 = (li1 < SCAP) ? slds[wid][li1] : srcs[beg + k + 1];
            uint4 v0[4], v1[4];
            #pragma unroll
            for (int ks = 0; ks < 4; ++ks) v0[ks] = xn4[(size_t)s0 * 16 + ks * 4 + lk];
            #pragma unroll
            for (int ks = 0; ks < 4; ++ks) v1[ks] = xn4[(size_t)s1 * 16 + ks * 4 + lk];
            #pragma unroll
            for (int ks = 0; ks < 4; ++ks) {
                acc[ks][0] += bflo(v0[ks].x) + bflo(v1[ks].x);
                acc[ks][1] += bfhi(v0[ks].x) + bfhi(v1[ks].x);
                acc[ks][2] += bflo(v0[ks].y) + bflo(v1[ks].y);
                acc[ks][3] += bfhi(v0[ks].y) + bfhi(v1[ks].y);
                acc[ks][4] += bflo(v0[ks].z) + bflo(v1[ks].z);
                acc[ks][5] += bfhi(v0[ks].z) + bfhi(v1[ks].z);
                acc[ks][6] += bflo(v0[ks].w) + bflo(v1[ks].w);
                acc[ks][7] += bfhi(v0[ks].w) + bfhi(v1[ks].w);
            }
        }
        if (k < n) {                           // tail edge
            int li0 = lbase + k;
            int s0 = (li0 < SCAP) ? slds[wid][li0] : srcs[beg + k];
            #pragma unroll
            for (int ks = 0; ks < 4; ++ks) {
                uint4 v = xn4[(size_t)s0 * 16 + ks * 4 + lk];
                acc[ks][0] += bflo(v.x); acc[ks][1] += bfhi(v.x);
                acc[ks][2] += bflo(v.y); acc[ks][3] += bfhi(v.y);
                acc[ks][4] += bflo(v.z); acc[ks][5] += bfhi(v.z);
                acc[ks][6] += bflo(v.w); acc[ks][7] += bfhi(v.w);
            }
        }

        // scale by dinv[node], convert to A-fragments
        bf16x8 a[4];
        #pragma unroll
        for (int ks = 0; ks < 4; ++ks)
            #pragma unroll
            for (int j = 0; j < 8; ++j) a[ks][j] = (short)f2bf(acc[ks][j] * di);

        f32x4 dacc[8];
        #pragma unroll
        for (int nt = 0; nt < 8; ++nt) dacc[nt] = (f32x4){0.f, 0.f, 0.f, 0.f};
        #pragma unroll
        for (int ks = 0; ks < 4; ++ks)
            #pragma unroll
            for (int nt = 0; nt < 8; ++nt) {
                int brow = nt * 16 + lm;
                bf16x8 bfr = *(const bf16x8*)(Wl + brow * 256 + ((ks * 64 + lk * 16) ^ ((brow & 7) << 4)));
                dacc[nt] = __builtin_amdgcn_mfma_f32_16x16x32_bf16(a[ks], bfr, dacc[nt], 0, 0, 0);
            }

        // epilogue: D row = lk*4+r, col = nt*16+lm (R13 order)
        #pragma unroll
        for (int nt = 0; nt < 8; ++nt)
            #pragma unroll
            for (int r = 0; r < 4; ++r) {
                float val = dacc[nt][r] + bb[nt];
                out[(size_t)(nbase + lk * 4 + r) * DD + nt * 16 + lm] = val;
                s8[nt] += val; ss8[nt] += val * val;
            }
    }

    // ---- stats: reduce across lk groups, then across waves (reusing W LDS)
    #pragma unroll
    for (int nt = 0; nt < 8; ++nt) {
        s8[nt]  += __shfl_xor(s8[nt], 16);  s8[nt]  += __shfl_xor(s8[nt], 32);
        ss8[nt] += __shfl_xor(ss8[nt], 16); ss8[nt] += __shfl_xor(ss8[nt], 32);
    }
    __syncthreads();                     // all waves done reading W
    float* sp = (float*)Wl4;             // [8][128] sums | [8][128] sumsq = 8 KB
    if (lk == 0) {
        #pragma unroll
        for (int nt = 0; nt < 8; ++nt) {
            sp[wid * 128 + nt * 16 + lm]        = s8[nt];
            sp[1024 + wid * 128 + nt * 16 + lm] = ss8[nt];
        }
    }
    __syncthreads();
    if (tid < 128) {
        float a = 0.0f, c = 0.0f;
        #pragma unroll
        for (int w = 0; w < 8; ++w) { a += sp[w * 128 + tid]; c += sp[1024 + w * 128 + tid]; }
        partial[(size_t)blockIdx.x * 256 + tid]       = a;
        partial[(size_t)blockIdx.x * 256 + 128 + tid] = c;
    }
}

// ---------------------------------------------------------------- reduce partials -> stats[256]
__global__ __launch_bounds__(256) void k_red(const float* __restrict__ partial,
                                             float* __restrict__ stats) {
    int tid = threadIdx.x;
    float a = 0.0f;
    for (int r = blockIdx.x; r < NBLK; r += 64)
        a += partial[(size_t)r * 256 + tid];
    unsafeAtomicAdd(&stats[tid], a);
}

// ---------------------------------------------------------------- BN apply + ReLU + residual
__global__ __launch_bounds__(256) void k_final(float* __restrict__ out,
                                               const float* __restrict__ x,
                                               const float* __restrict__ gamma,
                                               const float* __restrict__ beta,
                                               const float* __restrict__ stats) {
    int idx = blockIdx.x * 256 + threadIdx.x;
    if (idx >= NN * DD / 4) return;
    int c4 = idx & 31;

    const float invN = 1.0f / (float)NN;
    float4 sm  = ((const float4*)stats)[c4];
    float4 sq  = ((const float4*)stats)[32 + c4];
    float4 g   = ((const float4*)gamma)[c4];
    float4 be  = ((const float4*)beta)[c4];
    float4 v   = ((float4*)out)[idx];
    float4 xr  = ((const float4*)x)[idx];

    float m0 = sm.x * invN, m1 = sm.y * invN, m2 = sm.z * invN, m3 = sm.w * invN;
    float r0 = rsqrtf(sq.x * invN - m0 * m0 + BN_EPS);
    float r1 = rsqrtf(sq.y * invN - m1 * m1 + BN_EPS);
    float r2 = rsqrtf(sq.z * invN - m2 * m2 + BN_EPS);
    float r3 = rsqrtf(sq.w * invN - m3 * m3 + BN_EPS);

    float4 o;
    o.x = fmaxf((v.x - m0) * r0 * g.x + be.x, 0.0f) + xr.x;
    o.y = fmaxf((v.y - m1) * r1 * g.y + be.y, 0.0f) + xr.y;
    o.z = fmaxf((v.z - m2) * r2 * g.z + be.z, 0.0f) + xr.z;
    o.w = fmaxf((v.w - m3) * r3 * g.w + be.w, 0.0f) + xr.w;
    ((float4*)out)[idx] = o;
}

// ---------------------------------------------------------------- launch
extern "C" void kernel_launch(void* const* d_in, const int* in_sizes, int n_in,
                              void* d_out, int out_size, void* d_ws, size_t ws_size,
                              hipStream_t stream) {
    const float* x     = (const float*)d_in[0];
    const int*   ei    = (const int*)d_in[1];    // [2, NE]
    const float* W     = (const float*)d_in[2];
    const float* b     = (const float*)d_in[3];
    const float* gamma = (const float*)d_in[4];
    const float* beta  = (const float*)d_in[5];
    float*       out   = (float*)d_out;

    char*  base = (char*)d_ws;
    size_t off  = 0;
    auto carve = [&](size_t bytes) -> void* {
        void* p = base + off;
        off = (off + bytes + 255) & ~(size_t)255;
        return p;
    };
    unsigned short* xn    = (unsigned short*)carve((size_t)NN * DD * 2);   // 25.6 MB
    float*          dinv  = (float*)carve((size_t)NN * 4);
    float*          stats = (float*)carve(256 * 4);
    int*            cnt   = (int*)carve((size_t)NN * 4);
    int*            offs  = (int*)carve((size_t)(NN + 1) * 4);
    int*            rank  = (int*)carve((size_t)NE * 4);                   // 2.4 MB
    int*            bsum  = (int*)carve(2048);
    int*            srcs  = (int*)carve((size_t)(NE + NN) * 4);            // 2.8 MB
    unsigned short* Wt    = (unsigned short*)carve(DD * DD * 2);
    float*          partial = (float*)carve((size_t)NBLK * 256 * 4);       // 0.8 MB

    const int* src = ei;        // edge_index[0]
    const int* dst = ei + NE;   // edge_index[1]

    k_init   <<<NB1, 256, 0, stream>>>(cnt, stats, W, Wt);
    k_count  <<<(NE + 255) / 256, 256, 0, stream>>>(dst, cnt, rank);
    k_scan1  <<<NB1, 256, 0, stream>>>(cnt, offs, bsum);
    k_scan2  <<<1, 512, 0, stream>>>(bsum);
    k_scan3  <<<NB1, 256, 0, stream>>>(offs, bsum, cnt, dinv, srcs);
    k_cvfill <<<NFB + NCV, 256, 0, stream>>>(x, dinv, xn, src, dst, rank, offs, srcs);
    k_gather <<<NBLK, 512, 0, stream>>>(offs, srcs, xn, dinv, b, Wt, out, partial);
    k_red    <<<64, 256, 0, stream>>>(partial, stats);
    k_final  <<<(NN * DD / 4 + 255) / 256, 256, 0, stream>>>(out, x, gamma, beta, stats);
}